// Round 2
// baseline (445.588 us; speedup 1.0000x reference)
//
#include <hip/hip_runtime.h>
#include <hip/hip_bf16.h>
#include <stdint.h>

typedef __bf16 bf16x8 __attribute__((ext_vector_type(8)));
typedef float  f32x4  __attribute__((ext_vector_type(4)));

#define NSLOPE 0.01f

// problem dims
#define NB   32
#define CIN  128
#define HIN  130
#define WIN  130
#define KOUT 256
#define POUT 128
#define QOUT 128
#define HWIN (HIN*WIN)            // 16900

// workspace layout: X' (NHWC bf16) then W' ([cc][r][s][k][ci] bf16)
#define XP_BYTES 138444800ull     // 32*130*130*128*2
#define WP_ELEMS (2*3*3*KOUT*64)  // 294912

// LDS layout (dynamic, 132096 B): W dbuf 2x32768 @0, X dbuf 2x33280 @65536
#define WS_BYTES 32768
#define XS_BYTES 33280
#define XS_BASE  65536
#define LDS_TOTAL 132096

__device__ __forceinline__ unsigned short f2bf(float f) {
    unsigned u = __builtin_bit_cast(unsigned, f);
    u += 0x7FFFu + ((u >> 16) & 1u);   // RNE
    return (unsigned short)(u >> 16);
}

__device__ __forceinline__ void g2lds16(const void* g, void* l) {
    __builtin_amdgcn_global_load_lds(
        (const __attribute__((address_space(1))) void*)g,
        (__attribute__((address_space(3))) void*)l,
        16, 0, 0);
}

// ---------------- pre-pass 1: X NCHW fp32 -> NHWC bf16 ----------------
__global__ __launch_bounds__(256) void k_conv_x(const float* __restrict__ X,
                                                unsigned short* __restrict__ Xp) {
    __shared__ unsigned short tile[130*132];   // [w][c], c padded 128->132
    const int b = blockIdx.x;                  // n*130 + h
    const int n = b / 130, h = b - n*130;
    const int tid = threadIdx.x;
    const size_t in_base = (size_t)n*(CIN*(size_t)HWIN) + (size_t)h*WIN;
    for (int fi = tid; fi < CIN*WIN; fi += 256) {
        int c = fi / WIN, w = fi - c*WIN;
        tile[w*132 + c] = f2bf(X[in_base + (size_t)c*HWIN + w]);
    }
    __syncthreads();
    unsigned short* outp = Xp + (size_t)b * (WIN*CIN);
    for (int oi = tid; oi < (WIN*CIN)/4; oi += 256) {
        int e = oi*4; int w = e >> 7; int c4 = e & 127;
        const unsigned short* t = &tile[w*132 + c4];
        ushort4 v; v.x = t[0]; v.y = t[1]; v.z = t[2]; v.w = t[3];
        *(ushort4*)(outp + e) = v;
    }
}

// ---------------- pre-pass 2: W OIHW fp32 -> [cc][r][s][k][ci] bf16 ----------------
__global__ __launch_bounds__(256) void k_conv_w(const float* __restrict__ W,
                                                unsigned short* __restrict__ Wp) {
    int e = blockIdx.x*256 + threadIdx.x;
    if (e >= WP_ELEMS) return;
    int ci = e & 63;
    int k  = (e >> 6) & 255;
    int rsIdx = e >> 14;                       // 0..17 = cc*9 + r*3 + s
    int cc = rsIdx / 9; int rem = rsIdx - cc*9; int r = rem / 3, s = rem - r*3;
    int c = cc*64 + ci;
    Wp[e] = f2bf(W[(size_t)k*1152 + (size_t)c*9 + r*3 + s]);
}

// ---------------- staging helpers (linear LDS dest, inverse-swizzled global src) ----------------
// swizzle: phys = logical ^ ((row&7)<<4), row = phys>>7 (128 B rows)
__device__ __forceinline__ void stage_w_half(const unsigned short* __restrict__ Wp,
                                             unsigned char* lds, int rsidx, int tid, int half) {
    const unsigned short* wbase = Wp + (size_t)rsidx * (KOUT*64);
    #pragma unroll
    for (int it = half*2; it < half*2 + 2; ++it) {
        const int t    = it*512 + tid;
        const int phys = t << 4;
        const int row  = phys >> 7;                      // k 0..255
        const int cib  = (phys & 127) ^ ((row & 7) << 4);
        g2lds16(wbase + (size_t)row*64 + (cib >> 1), lds + phys);
    }
}

__device__ __forceinline__ void stage_x(const unsigned short* __restrict__ Xp,
                                        unsigned char* lds, int n, int h0, int cc, int tid) {
    #pragma unroll
    for (int it = 0; it < 5; ++it) {
        const int t = it*512 + tid;
        if (t < 2080) {                                  // 260 rows x 8 granules
            const int phys = t << 4;
            const int g    = phys >> 7;                  // p_local*130 + w
            const int pl   = (g >= 130) ? 1 : 0;
            const int w    = g - 130*pl;
            const int cib  = (phys & 127) ^ ((g & 7) << 4);
            const unsigned short* src =
                Xp + ((size_t)((n*HIN + h0 + pl)*WIN + w))*CIN + cc*64 + (cib >> 1);
            g2lds16(src, lds + phys);
        }
    }
}

// ---------------- main conv: implicit GEMM, 256x256 tile, 8 waves, phased pipeline ----------------
__global__ __launch_bounds__(512, 2) void k_conv_main(
    const unsigned short* __restrict__ Xp,
    const unsigned short* __restrict__ Wp,
    const float* __restrict__ bias,
    float* __restrict__ out)
{
    extern __shared__ __align__(16) unsigned char smem[];

    const int tid  = threadIdx.x;
    const int lane = tid & 63;
    const int wid  = tid >> 6;
    const int wm   = wid >> 2;         // kout 128-half
    const int wn   = wid & 3;          // q 64-block (of 256 = 2 p rows x 128 q)
    const int l15  = lane & 15;
    const int kg   = lane >> 4;

    // bijective XCD swizzle (2048 = 8 x 256)
    const int L     = ((blockIdx.x & 7) << 8) | (blockIdx.x >> 3);
    const int ppair = L & 63;
    const int n     = L >> 6;
    const int p2    = ppair << 1;

    f32x4 acc[8][4];
    #pragma unroll
    for (int i = 0; i < 8; ++i)
        #pragma unroll
        for (int j = 0; j < 4; ++j)
            acc[i][j] = (f32x4){0.f, 0.f, 0.f, 0.f};

    // prologue: stage W[0] + X[cc=0,r=0]
    stage_w_half(Wp, smem, 0, tid, 0);
    stage_w_half(Wp, smem, 0, tid, 1);
    stage_x(Xp, smem + XS_BASE, n, p2, 0, tid);
    asm volatile("s_waitcnt vmcnt(0)" ::: "memory");
    __builtin_amdgcn_s_barrier();

    for (int t = 0; t < 18; ++t) {
        const int cc  = t / 9;
        const int rem = t - cc*9;
        const int s   = rem % 3;
        unsigned char* wsR = smem + (t & 1)*WS_BYTES;
        unsigned char* xsR = smem + XS_BASE + (((unsigned)t/3) & 1)*XS_BYTES;
        const int  tn    = t + 1;
        const bool haveW = (tn < 18);
        const bool haveX = haveW && (tn % 3 == 0);
        unsigned char* wsW = smem + (tn & 1)*WS_BYTES;
        unsigned char* xsW = smem + XS_BASE + (((unsigned)tn/3) & 1)*XS_BYTES;

        #pragma unroll
        for (int kq = 0; kq < 2; ++kq) {
            const int cib0 = kq*64 + kg*16;
            bf16x8 af[8], bx[4];
            #pragma unroll
            for (int mf = 0; mf < 8; ++mf) {   // A = W rows (kout)
                const int row = wm*128 + mf*16 + l15;
                af[mf] = *(const bf16x8*)(wsR + row*128 + (cib0 ^ ((row & 7) << 4)));
            }
            #pragma unroll
            for (int nf = 0; nf < 4; ++nf) {   // B = X cols (q), w = q + s
                const int qq   = wn*64 + nf*16 + l15;
                const int row2 = (qq >> 7)*130 + (qq & 127) + s;
                bx[nf] = *(const bf16x8*)(xsR + row2*128 + (cib0 ^ ((row2 & 7) << 4)));
            }
            // prefetch next step's tiles into the other buffers (counted: drained at step end)
            if (haveW) stage_w_half(Wp, wsW, tn, tid, kq);
            if (kq == 1 && haveX) stage_x(Xp, xsW, n, p2 + (tn % 9) / 3, tn / 9, tid);

            __builtin_amdgcn_s_barrier();
            asm volatile("s_waitcnt lgkmcnt(0)" ::: "memory");
            __builtin_amdgcn_sched_barrier(0);
            __builtin_amdgcn_s_setprio(1);
            #pragma unroll
            for (int mf = 0; mf < 8; ++mf)
                #pragma unroll
                for (int nf = 0; nf < 4; ++nf)
                    acc[mf][nf] = __builtin_amdgcn_mfma_f32_16x16x32_bf16(
                        af[mf], bx[nf], acc[mf][nf], 0, 0, 0);
            __builtin_amdgcn_s_setprio(0);
            if (kq == 1)
                asm volatile("s_waitcnt vmcnt(0)" ::: "memory");  // next-step loads landed
            __builtin_amdgcn_s_barrier();
        }
    }

    // epilogue: D col = q16 = lane&15, row = kout = kg*4 + j  ->  coalesced 64-B segments
    #pragma unroll
    for (int mf = 0; mf < 8; ++mf) {
        const int kb = wm*128 + mf*16 + kg*4;
        const float4 bv = *(const float4*)(bias + kb);
        const float bj[4] = {bv.x, bv.y, bv.z, bv.w};
        #pragma unroll
        for (int nf = 0; nf < 4; ++nf) {
            const int qq = wn*64 + nf*16 + l15;
            const int pl = qq >> 7, q = qq & 127;
            const size_t base = (((size_t)n*KOUT + kb)*POUT + (p2 + pl))*QOUT + q;
            #pragma unroll
            for (int j = 0; j < 4; ++j) {
                float y = (acc[mf][nf][j] + bj[j]) * 0.5f;
                out[base + (size_t)j*(POUT*QOUT)] = (y >= 0.f) ? y : y*NSLOPE;
            }
        }
    }
}

extern "C" void kernel_launch(void* const* d_in, const int* in_sizes, int n_in,
                              void* d_out, int out_size, void* d_ws, size_t ws_size,
                              hipStream_t stream) {
    const float* X = (const float*)d_in[0];
    const float* W = (const float*)d_in[1];
    const float* B = (const float*)d_in[2];
    float* out = (float*)d_out;
    unsigned short* Xp = (unsigned short*)d_ws;
    unsigned short* Wp = (unsigned short*)((char*)d_ws + XP_BYTES);

    (void)hipFuncSetAttribute((const void*)k_conv_main,
                              hipFuncAttributeMaxDynamicSharedMemorySize, LDS_TOTAL);

    k_conv_x   <<<NB*HIN, 256, 0, stream>>>(X, Xp);
    k_conv_w   <<<(WP_ELEMS + 255)/256, 256, 0, stream>>>(W, Wp);
    k_conv_main<<<2048, 512, LDS_TOTAL, stream>>>(Xp, Wp, B, out);
}

// Round 3
// 444.455 us; speedup vs baseline: 1.0025x; 1.0025x over previous
//
#include <hip/hip_runtime.h>
#include <hip/hip_bf16.h>
#include <stdint.h>

typedef __bf16 bf16x8 __attribute__((ext_vector_type(8)));
typedef float  f32x4  __attribute__((ext_vector_type(4)));

#define NSLOPE 0.01f

// problem dims
#define NB   32
#define CIN  128
#define HIN  130
#define WIN  130
#define KOUT 256
#define POUT 128
#define QOUT 128
#define HWIN (HIN*WIN)            // 16900

// workspace layout: X' (NHWC bf16) then W' ([cc][r][s][k][ci] bf16)
#define XP_BYTES 138444800ull     // 32*130*130*128*2
#define WP_ELEMS (2*3*3*KOUT*64)  // 294912

// LDS layout (dynamic, 132096 B): W dbuf 2x32768 @0, X slab (4 h-rows) 66560 @65536
#define WS_BYTES 32768
#define XS_BASE  65536
#define LDS_TOTAL 132096

__device__ __forceinline__ unsigned short f2bf(float f) {
    unsigned u = __builtin_bit_cast(unsigned, f);
    u += 0x7FFFu + ((u >> 16) & 1u);   // RNE
    return (unsigned short)(u >> 16);
}

__device__ __forceinline__ void g2lds16(const void* g, void* l) {
    __builtin_amdgcn_global_load_lds(
        (const __attribute__((address_space(1))) void*)g,
        (__attribute__((address_space(3))) void*)l,
        16, 0, 0);
}

// ---------------- pre-pass 1: X NCHW fp32 -> NHWC bf16 ----------------
__global__ __launch_bounds__(256) void k_conv_x(const float* __restrict__ X,
                                                unsigned short* __restrict__ Xp) {
    __shared__ unsigned short tile[130*132];   // [w][c], c padded 128->132
    const int b = blockIdx.x;                  // n*130 + h
    const int n = b / 130, h = b - n*130;
    const int tid = threadIdx.x;
    const size_t in_base = (size_t)n*(CIN*(size_t)HWIN) + (size_t)h*WIN;
    for (int fi = tid; fi < CIN*WIN; fi += 256) {
        int c = fi / WIN, w = fi - c*WIN;
        tile[w*132 + c] = f2bf(X[in_base + (size_t)c*HWIN + w]);
    }
    __syncthreads();
    unsigned short* outp = Xp + (size_t)b * (WIN*CIN);
    for (int oi = tid; oi < (WIN*CIN)/4; oi += 256) {
        int e = oi*4; int w = e >> 7; int c4 = e & 127;
        const unsigned short* t = &tile[w*132 + c4];
        ushort4 v; v.x = t[0]; v.y = t[1]; v.z = t[2]; v.w = t[3];
        *(ushort4*)(outp + e) = v;
    }
}

// ---------------- pre-pass 2: W OIHW fp32 -> [cc][r][s][k][ci] bf16 ----------------
__global__ __launch_bounds__(256) void k_conv_w(const float* __restrict__ W,
                                                unsigned short* __restrict__ Wp) {
    int e = blockIdx.x*256 + threadIdx.x;
    if (e >= WP_ELEMS) return;
    int ci = e & 63;
    int k  = (e >> 6) & 255;
    int rsIdx = e >> 14;                       // 0..17 = cc*9 + r*3 + s
    int cc = rsIdx / 9; int rem = rsIdx - cc*9; int r = rem / 3, s = rem - r*3;
    int c = cc*64 + ci;
    Wp[e] = f2bf(W[(size_t)k*1152 + (size_t)c*9 + r*3 + s]);
}

// ---------------- staging helpers (linear LDS dest, inverse-swizzled global src) ----------------
// swizzle: phys = logical ^ ((row&7)<<4), row = phys>>7 (128 B rows)
__device__ __forceinline__ void stage_w_half(const unsigned short* __restrict__ Wp,
                                             unsigned char* lds, int rsidx, int tid, int half) {
    const unsigned short* wbase = Wp + (size_t)rsidx * (KOUT*64);
    #pragma unroll
    for (int it = half*2; it < half*2 + 2; ++it) {
        const int t    = it*512 + tid;
        const int phys = t << 4;
        const int row  = phys >> 7;                      // k 0..255
        const int cib  = (phys & 127) ^ ((row & 7) << 4);
        g2lds16(wbase + (size_t)row*64 + (cib >> 1), lds + phys);
    }
}

// stage 4 h-rows (p2..p2+3), all 130 w, 64 ci of channel-half cc: 4160 granules
__device__ __forceinline__ void stage_x4(const unsigned short* __restrict__ Xp,
                                         unsigned char* lds, int n, int p2, int cc, int tid) {
    #pragma unroll
    for (int it = 0; it < 9; ++it) {
        const int t = it*512 + tid;
        if (t < 4160) {
            const int phys = t << 4;
            const int g    = phys >> 7;                  // rloc*130 + w, 0..519
            const int rloc = g / 130;
            const int w    = g - 130*rloc;
            const int cib  = (phys & 127) ^ ((g & 7) << 4);
            const unsigned short* src =
                Xp + ((size_t)((n*HIN + p2 + rloc)*WIN + w))*CIN + cc*64 + (cib >> 1);
            g2lds16(src, lds + phys);
        }
    }
}

// ---------------- main conv: implicit GEMM, 256x256 tile, 8 waves, 4-phase pipeline ----------------
__global__ __launch_bounds__(512, 2) void k_conv_main(
    const unsigned short* __restrict__ Xp,
    const unsigned short* __restrict__ Wp,
    const float* __restrict__ bias,
    float* __restrict__ out)
{
    extern __shared__ __align__(16) unsigned char smem[];

    const int tid  = threadIdx.x;
    const int lane = tid & 63;
    const int wid  = tid >> 6;
    const int wm   = wid >> 2;         // kout 128-half
    const int wn   = wid & 3;          // q 64-block (of 256 = 2 p rows x 128 q)
    const int l15  = lane & 15;
    const int kg   = lane >> 4;

    // bijective XCD swizzle (2048 = 8 x 256)
    const int L     = ((blockIdx.x & 7) << 8) | (blockIdx.x >> 3);
    const int ppair = L & 63;
    const int n     = L >> 6;
    const int p2    = ppair << 1;

    unsigned char* xs = smem + XS_BASE;

    f32x4 acc[8][4];
    #pragma unroll
    for (int i = 0; i < 8; ++i)
        #pragma unroll
        for (int j = 0; j < 4; ++j)
            acc[i][j] = (f32x4){0.f, 0.f, 0.f, 0.f};

    // prologue: stage W[0] into buf0 + X slab (cc=0)
    stage_w_half(Wp, smem, 0, tid, 0);
    stage_w_half(Wp, smem, 0, tid, 1);
    stage_x4(Xp, xs, n, p2, 0, tid);
    asm volatile("s_waitcnt vmcnt(0)" ::: "memory");
    __builtin_amdgcn_s_barrier();

    for (int t = 0; t < 18; ++t) {
        const int cc  = t / 9;
        const int rem = t - cc*9;
        const int rr  = rem / 3;
        const int s   = rem - rr*3;
        unsigned char* wsR = smem + (t & 1)*WS_BYTES;
        const bool haveW   = (t + 1 < 18);
        unsigned char* wsW = smem + ((t + 1) & 1)*WS_BYTES;

        #pragma unroll
        for (int kq = 0; kq < 2; ++kq) {
            const int cib0 = kq*64 + kg*16;
            bf16x8 afA[4], afB[4], bx[4];

            // ---- phase A: 4 A-frags + 4 B-frags; issue W prefetch half 0 ----
            #pragma unroll
            for (int mf = 0; mf < 4; ++mf) {
                const int row = wm*128 + mf*16 + l15;
                afA[mf] = *(const bf16x8*)(wsR + row*128 + (cib0 ^ ((row & 7) << 4)));
            }
            #pragma unroll
            for (int nf = 0; nf < 4; ++nf) {
                const int qq = wn*64 + nf*16 + l15;
                const int g  = ((qq >> 7) + rr)*130 + (qq & 127) + s;
                bx[nf] = *(const bf16x8*)(xs + g*128 + (cib0 ^ ((g & 7) << 4)));
            }
            if (haveW && kq == 0) stage_w_half(Wp, wsW, t + 1, tid, 0);
            __builtin_amdgcn_s_barrier();
            asm volatile("s_waitcnt lgkmcnt(0)" ::: "memory");
            __builtin_amdgcn_sched_barrier(0);
            __builtin_amdgcn_s_setprio(1);
            #pragma unroll
            for (int mf = 0; mf < 4; ++mf)
                #pragma unroll
                for (int nf = 0; nf < 4; ++nf)
                    acc[mf][nf] = __builtin_amdgcn_mfma_f32_16x16x32_bf16(
                        afA[mf], bx[nf], acc[mf][nf], 0, 0, 0);
            __builtin_amdgcn_s_setprio(0);
            __builtin_amdgcn_s_barrier();

            // ---- phase B: 4 A-frags; issue W prefetch half 1 ----
            #pragma unroll
            for (int mf = 0; mf < 4; ++mf) {
                const int row = wm*128 + (mf + 4)*16 + l15;
                afB[mf] = *(const bf16x8*)(wsR + row*128 + (cib0 ^ ((row & 7) << 4)));
            }
            if (haveW && kq == 0) stage_w_half(Wp, wsW, t + 1, tid, 1);
            __builtin_amdgcn_s_barrier();
            asm volatile("s_waitcnt lgkmcnt(0)" ::: "memory");
            __builtin_amdgcn_sched_barrier(0);
            __builtin_amdgcn_s_setprio(1);
            #pragma unroll
            for (int mf = 0; mf < 4; ++mf)
                #pragma unroll
                for (int nf = 0; nf < 4; ++nf)
                    acc[mf + 4][nf] = __builtin_amdgcn_mfma_f32_16x16x32_bf16(
                        afB[mf], bx[nf], acc[mf + 4][nf], 0, 0, 0);
            __builtin_amdgcn_s_setprio(0);
            if (kq == 1)
                asm volatile("s_waitcnt vmcnt(0)" ::: "memory");  // W t+1 landed
            __builtin_amdgcn_s_barrier();
        }

        if (t == 8) {   // cc boundary: restage X slab for cc=1 (one-time drain)
            stage_x4(Xp, xs, n, p2, 1, tid);
            asm volatile("s_waitcnt vmcnt(0)" ::: "memory");
            __builtin_amdgcn_s_barrier();
        }
    }

    // epilogue: D col = q16 = lane&15, row = kout = kg*4 + j  ->  coalesced 64-B segments
    #pragma unroll
    for (int mf = 0; mf < 8; ++mf) {
        const int kb = wm*128 + mf*16 + kg*4;
        const float4 bv = *(const float4*)(bias + kb);
        const float bj[4] = {bv.x, bv.y, bv.z, bv.w};
        #pragma unroll
        for (int nf = 0; nf < 4; ++nf) {
            const int qq = wn*64 + nf*16 + l15;
            const int pl = qq >> 7, q = qq & 127;
            const size_t base = (((size_t)n*KOUT + kb)*POUT + (p2 + pl))*QOUT + q;
            #pragma unroll
            for (int j = 0; j < 4; ++j) {
                float y = (acc[mf][nf][j] + bj[j]) * 0.5f;
                out[base + (size_t)j*(POUT*QOUT)] = (y >= 0.f) ? y : y*NSLOPE;
            }
        }
    }
}

extern "C" void kernel_launch(void* const* d_in, const int* in_sizes, int n_in,
                              void* d_out, int out_size, void* d_ws, size_t ws_size,
                              hipStream_t stream) {
    const float* X = (const float*)d_in[0];
    const float* W = (const float*)d_in[1];
    const float* B = (const float*)d_in[2];
    float* out = (float*)d_out;
    unsigned short* Xp = (unsigned short*)d_ws;
    unsigned short* Wp = (unsigned short*)((char*)d_ws + XP_BYTES);

    (void)hipFuncSetAttribute((const void*)k_conv_main,
                              hipFuncAttributeMaxDynamicSharedMemorySize, LDS_TOTAL);

    k_conv_x   <<<NB*HIN, 256, 0, stream>>>(X, Xp);
    k_conv_w   <<<(WP_ELEMS + 255)/256, 256, 0, stream>>>(W, Wp);
    k_conv_main<<<2048, 512, LDS_TOTAL, stream>>>(Xp, Wp, B, out);
}